// Round 5
// baseline (297.882 us; speedup 1.0000x reference)
//
#include <hip/hip_runtime.h>
#include <hip/hip_bf16.h>
#include <math.h>

#define BSZ  16
#define LSEQ 4096
#define DM   1024
#define DS   64
#define CHK  64     // rows per k_fir block
#define NCHK 64     // LSEQ / CHK
#define FK   12     // FIR horizon: ||A||^12 ~ 3e-10, far below bf16 state LSB
#define FIXT 8      // cross-chunk fix horizon

typedef __bf16 bf16;
typedef bf16  bf16x8 __attribute__((ext_vector_type(8)));
typedef bf16  bf16x4 __attribute__((ext_vector_type(4)));
typedef float f32x4  __attribute__((ext_vector_type(4)));

#define MFMA(a,b,c) __builtin_amdgcn_mfma_f32_16x16x32_bf16((a),(b),(c),0,0,0)

// ---------------- K0: convert B_mat and C to bf16 ----------------
__global__ __launch_bounds__(256) void k_prep(const float* __restrict__ Bm,
                                              const float* __restrict__ Cm,
                                              bf16* __restrict__ Bh,
                                              bf16* __restrict__ Ch) {
    int i = blockIdx.x * 256 + threadIdx.x;   // grid covers DS*DM = 65536
    Bh[i] = (bf16)Bm[i];
    Ch[i] = (bf16)Cm[i];
}

// ---------------- K1: Apow[k] = A^k (bf16), k = 0..FK-1; one block ----------------
__global__ __launch_bounds__(1024) void k_apow(const float* __restrict__ A,
                                               bf16* __restrict__ Apow) {
    __shared__ float P0[64 * 64], P1[64 * 64];
    const int tid = threadIdx.x;
    const int i = tid >> 4, j4 = (tid & 15) * 4;

    #pragma unroll
    for (int q = 0; q < 4; ++q) {
        int j = j4 + q;
        Apow[i * 64 + j] = (bf16)((i == j) ? 1.f : 0.f);   // A^0 = I
        P0[i * 64 + j]   = A[i * 64 + j];                  // cur = A^1
    }
    __syncthreads();

    float* cur = P0; float* nxt = P1;
    for (int k = 1; k < FK; ++k) {
        const float4 v = *(const float4*)&cur[i * 64 + j4];
        Apow[k * 4096 + i * 64 + j4 + 0] = (bf16)v.x;      // emit A^k
        Apow[k * 4096 + i * 64 + j4 + 1] = (bf16)v.y;
        Apow[k * 4096 + i * 64 + j4 + 2] = (bf16)v.z;
        Apow[k * 4096 + i * 64 + j4 + 3] = (bf16)v.w;
        float a0 = 0.f, a1 = 0.f, a2 = 0.f, a3 = 0.f;      // nxt = A * cur
        for (int m = 0; m < 64; ++m) {
            const float am = A[i * 64 + m];
            const float4 cr = *(const float4*)&cur[m * 64 + j4];
            a0 = fmaf(am, cr.x, a0);
            a1 = fmaf(am, cr.y, a1);
            a2 = fmaf(am, cr.z, a2);
            a3 = fmaf(am, cr.w, a3);
        }
        __syncthreads();
        nxt[i * 64 + j4 + 0] = a0;
        nxt[i * 64 + j4 + 1] = a1;
        nxt[i * 64 + j4 + 2] = a2;
        nxt[i * 64 + j4 + 3] = a3;
        __syncthreads();
        float* t = cur; cur = nxt; nxt = t;
    }
}

// ---------------- K2: fused xu GEMM + FIR-matmul scan (no serialization) --------
// Wave w owns rows w*16..w*16+15 of the 64-row chunk.
// Stage 1: u = x @ B^T, x read global->reg->bf16 (no LDS staging, no barriers).
// Stage 2: states[t] = sum_{k<FK} u[t-k] @ (A^k)^T via MFMA; triangular masking
//          through 12 zeroed LDS halo rows. Cross-chunk carry handled by k_fix.
__global__ __launch_bounds__(256) void k_fir(const float* __restrict__ x,
                                             const bf16* __restrict__ Bh,
                                             const bf16* __restrict__ Apow,
                                             bf16* __restrict__ states) {
    const int c = blockIdx.x, b = blockIdx.y;
    const int tid = threadIdx.x, lane = tid & 63, w = tid >> 6;
    const int fr = lane & 15;
    const int kg = (lane >> 4) * 8;
    const int rg = (lane >> 4) * 4;

    __shared__ __align__(16) bf16 ulds[76][72];   // rows 0..11 zero halo, 12.. = u
    __shared__ __align__(16) bf16 slds[64][72];   // states transpose buffer

    // zero the 12 halo rows (12*144 = 1728 B)
    if (tid < 216) *(float2*)((char*)ulds + tid * 8) = make_float2(0.f, 0.f);

    // ---- stage 1: u rows (this wave: w*16+fr), K = 1024 ----
    const float* xrow  = x  + (size_t)(b * LSEQ + c * CHK + w * 16 + fr) * DM + kg;
    const bf16*  bbase = Bh + (size_t)fr * DM + kg;

    f32x4 acc[4] = {};
    #pragma unroll 4
    for (int ks = 0; ks < 1024; ks += 32) {
        float4 lo = *(const float4*)(xrow + ks);
        float4 hi = *(const float4*)(xrow + ks + 4);
        bf16x8 af = {(bf16)lo.x, (bf16)lo.y, (bf16)lo.z, (bf16)lo.w,
                     (bf16)hi.x, (bf16)hi.y, (bf16)hi.z, (bf16)hi.w};
        #pragma unroll
        for (int nt = 0; nt < 4; ++nt) {
            bf16x8 bf = *(const bf16x8*)(bbase + (size_t)nt * 16 * DM + ks);
            acc[nt] = MFMA(af, bf, acc[nt]);
        }
    }

    // u tile -> LDS bf16 (row = t-local + 12, col = s')
    #pragma unroll
    for (int nt = 0; nt < 4; ++nt)
        #pragma unroll
        for (int q = 0; q < 4; ++q)
            ulds[12 + w * 16 + rg + q][nt * 16 + fr] = (bf16)acc[nt][q];
    __syncthreads();

    // ---- stage 2: states = FIR over u with A-powers ----
    const bf16* apb = Apow + (size_t)fr * DS + kg;   // + nt*16*DS + k*4096 (+32 ks)
    f32x4 acc2[4] = {};
    #pragma unroll
    for (int k = 0; k < FK; ++k) {
        const int r0 = 12 + w * 16 - k;
        bf16x8 a0 = *(const bf16x8*)&ulds[r0 + fr][kg];        // s' 0..31 chunk
        bf16x8 a1 = *(const bf16x8*)&ulds[r0 + fr][32 + kg];   // s' 32..63 chunk
        #pragma unroll
        for (int nt = 0; nt < 4; ++nt) {
            bf16x8 b0 = *(const bf16x8*)(apb + (size_t)k * 4096 + nt * 16 * DS);
            bf16x8 b1 = *(const bf16x8*)(apb + (size_t)k * 4096 + nt * 16 * DS + 32);
            acc2[nt] = MFMA(a0, b0, acc2[nt]);
            acc2[nt] = MFMA(a1, b1, acc2[nt]);
        }
    }

    // states tile -> LDS (row = t-local, col = s), then coalesced global store
    #pragma unroll
    for (int nt = 0; nt < 4; ++nt)
        #pragma unroll
        for (int q = 0; q < 4; ++q)
            slds[w * 16 + rg + q][nt * 16 + fr] = (bf16)acc2[nt][q];
    __syncthreads();

    const int r  = tid >> 2;
    const int c0 = (tid & 3) * 16;
    bf16x8 s0 = *(const bf16x8*)&slds[r][c0];
    bf16x8 s1 = *(const bf16x8*)&slds[r][c0 + 8];
    bf16* sp = states + (size_t)(b * LSEQ + c * CHK + r) * DS + c0;
    *(bf16x8*)sp       = s0;
    *(bf16x8*)(sp + 8) = s1;
}

// ---------------- scan step helper (k_fix only): s' = A s + u ----------------
__device__ __forceinline__ float scan_step(const float* a, float s, float u) {
    float p0 = u, p1 = 0.f, p2 = 0.f, p3 = 0.f;
    #pragma unroll
    for (int j = 0; j < 64; j += 4) {
        p0 = fmaf(a[j + 0], __shfl(s, j + 0), p0);
        p1 = fmaf(a[j + 1], __shfl(s, j + 1), p1);
        p2 = fmaf(a[j + 2], __shfl(s, j + 2), p2);
        p3 = fmaf(a[j + 3], __shfl(s, j + 3), p3);
    }
    return (p0 + p1) + (p2 + p3);
}

// ---------------- K3: cross-chunk fixup: add A^(t+1)*carry, t < FIXT ------------
__global__ __launch_bounds__(64) void k_fix(const float* __restrict__ A,
                                            bf16* __restrict__ states) {
    const int c = blockIdx.x + 1, b = blockIdx.y, lane = threadIdx.x;
    float a[64];
    #pragma unroll
    for (int j4 = 0; j4 < 16; ++j4) {
        float4 v = *(const float4*)&A[lane * 64 + j4 * 4];
        a[j4*4+0] = v.x; a[j4*4+1] = v.y; a[j4*4+2] = v.z; a[j4*4+3] = v.w;
    }
    // carry = previous chunk's final state (row c*64-1); k_fix never writes row 63
    float v = (float)states[(size_t)(b * LSEQ + c * CHK - 1) * DS + lane];
    bf16* sp = states + (size_t)(b * LSEQ + c * CHK) * DS + lane;
    #pragma unroll
    for (int t = 0; t < FIXT; ++t) {
        v = scan_step(a, v, 0.f);
        float snew = (float)sp[t * DS] + v;
        sp[t * DS] = (bf16)snew;
    }
}

// ---------------- K4: y = st @ C^T, GELU, LN; LDS transpose -> coalesced stores --
__global__ __launch_bounds__(256) void k_out(const bf16* __restrict__ st,
                                             const bf16* __restrict__ Ch,
                                             const float* __restrict__ gamma,
                                             const float* __restrict__ beta,
                                             float* __restrict__ out) {
    const int R = blockIdx.x * 16;
    const int tid = threadIdx.x, lane = tid & 63, wave = tid >> 6;
    const int fr = lane & 15;
    const int kg = (lane >> 4) * 8;
    const int rg = (lane >> 4) * 4;

    __shared__ bf16  act[64 * 16 * 16];     // [d-tile 0..63][row16][dloc16], swizzled
    __shared__ float redS[4][16], redQ[4][16];
    __shared__ float meanL[16], rstdL[16];

    bf16x8 b0 = *(const bf16x8*)&st[(size_t)(R + fr) * DS + kg];
    bf16x8 b1 = *(const bf16x8*)&st[(size_t)(R + fr) * DS + 32 + kg];

    float sum = 0.f, sq = 0.f;
    const int nbase = wave * 256;

    #pragma unroll
    for (int nt = 0; nt < 16; ++nt) {
        const int d0 = nbase + nt * 16 + fr;
        bf16x8 a0 = *(const bf16x8*)&Ch[(size_t)d0 * DS + kg];
        bf16x8 a1 = *(const bf16x8*)&Ch[(size_t)d0 * DS + 32 + kg];
        f32x4 t = (f32x4){0.f, 0.f, 0.f, 0.f};
        t = MFMA(a0, b0, t);                // reg axis = d, lane axis = L row
        t = MFMA(a1, b1, t);

        bf16x4 av;
        #pragma unroll
        for (int q = 0; q < 4; ++q) {
            float v = t[q];
            float g = 0.5f * v * (1.f + erff(v * 0.70710678118654752f));
            sum += g; sq += g * g;          // stats from pre-rounding f32
            av[q] = (bf16)g;
        }
        const int ntg = wave * 16 + nt;
        int byte = ntg * 512 + fr * 32 + rg * 2;
        byte ^= (ntg & 7) << 4;             // bank swizzle
        *(bf16x4*)((char*)act + byte) = av;
    }

    sum += __shfl_xor(sum, 16); sq += __shfl_xor(sq, 16);
    sum += __shfl_xor(sum, 32); sq += __shfl_xor(sq, 32);
    if (lane < 16) { redS[wave][fr] = sum; redQ[wave][fr] = sq; }
    __syncthreads();

    if (tid < 16) {
        float S = redS[0][tid] + redS[1][tid] + redS[2][tid] + redS[3][tid];
        float Q = redQ[0][tid] + redQ[1][tid] + redQ[2][tid] + redQ[3][tid];
        float mu  = S * (1.f / 1024.f);
        float var = Q * (1.f / 1024.f) - mu * mu;
        meanL[tid] = mu;
        rstdL[tid] = rsqrtf(var + 1e-5f);
    }
    __syncthreads();

    #pragma unroll
    for (int rr = 0; rr < 4; ++rr) {
        const int r = wave * 4 + rr;
        const float mu = meanL[r], rs = rstdL[r];
        #pragma unroll
        for (int half = 0; half < 2; ++half) {
            const int d = half * 512 + lane * 8;
            const int ntg = d >> 4;
            int byte = ntg * 512 + r * 32 + (lane & 1) * 16;
            byte ^= (ntg & 7) << 4;
            bf16x8 av = *(const bf16x8*)((char*)act + byte);

            float4 g0  = *(const float4*)&gamma[d];
            float4 g1  = *(const float4*)&gamma[d + 4];
            float4 be0 = *(const float4*)&beta[d];
            float4 be1 = *(const float4*)&beta[d + 4];
            float4 o0, o1;
            o0.x = ((float)av[0] - mu) * rs * g0.x + be0.x;
            o0.y = ((float)av[1] - mu) * rs * g0.y + be0.y;
            o0.z = ((float)av[2] - mu) * rs * g0.z + be0.z;
            o0.w = ((float)av[3] - mu) * rs * g0.w + be0.w;
            o1.x = ((float)av[4] - mu) * rs * g1.x + be1.x;
            o1.y = ((float)av[5] - mu) * rs * g1.y + be1.y;
            o1.z = ((float)av[6] - mu) * rs * g1.z + be1.z;
            o1.w = ((float)av[7] - mu) * rs * g1.w + be1.w;

            float* orow = out + (size_t)(R + r) * DM + d;
            *(float4*)orow       = o0;
            *(float4*)(orow + 4) = o1;
        }
    }
}

// ---------------- launch ----------------
extern "C" void kernel_launch(void* const* d_in, const int* in_sizes, int n_in,
                              void* d_out, int out_size, void* d_ws, size_t ws_size,
                              hipStream_t stream) {
    (void)in_sizes; (void)n_in; (void)out_size; (void)ws_size;
    const float* x     = (const float*)d_in[0];
    const float* A     = (const float*)d_in[1];
    const float* Bm    = (const float*)d_in[2];
    const float* Cm    = (const float*)d_in[3];
    const float* gamma = (const float*)d_in[4];
    const float* beta  = (const float*)d_in[5];
    float* out = (float*)d_out;

    char* ws = (char*)d_ws;
    bf16* states = (bf16*)(ws);                   // 8 MB  [B][L][S] bf16
    bf16* Bh     = (bf16*)(ws + 8388608);         // 128 KB [S][D] bf16
    bf16* Ch     = (bf16*)(ws + 8519680);         // 128 KB [D][S] bf16
    bf16* Apow   = (bf16*)(ws + 8650752);         // 96 KB  [FK][64][64] bf16

    k_prep<<<dim3(256),           dim3(256),  0, stream>>>(Bm, Cm, Bh, Ch);
    k_apow<<<dim3(1),             dim3(1024), 0, stream>>>(A, Apow);
    k_fir <<<dim3(NCHK, BSZ),     dim3(256),  0, stream>>>(x, Bh, Apow, states);
    k_fix <<<dim3(NCHK - 1, BSZ), dim3(64),   0, stream>>>(A, states);
    k_out <<<dim3(4096),          dim3(256),  0, stream>>>(states, Ch, gamma, beta, out);
}